// Round 16
// baseline (95.252 us; speedup 1.0000x reference)
//
#include <hip/hip_runtime.h>
#include <stdint.h>

// Binarized dense via i8 MFMA: C[r][u] = dot(sign(x[r,:]), sign(W[:,u])) + b[u]
// sign in {+1,-1} as i8 0x01/0xFF; i32 accumulation exact (|dot| <= 4096).
// v_mfma_i32_32x32x32_i8: A/B = v4i (16 i8), lane&31 = row/col, lane>>5 =
// k-16-half; C/D: col = lane&31, row = (r&3)+8*(r>>2)+4*(lane>>5).
// All layouts/maps HW-verified (rounds 12-15, absmax 0).
//
// v11 = v10 with the vmcnt ORDERING fix:
// vmcnt waits are ordered: waiting for a load drains ALL OLDER loads first.
// v10 issued the 4 x HBM loads (~900cy) at period TOP, i.e. OLDER than every
// B load of the period -> each cluster's wait-for-B drained the x queue ->
// memory completed serially at pipe rate (x 1600 + B 4570 cy/period) with
// matrix barely overlapped (measured 12.7k cyc/period).
// Now x loads are issued AFTER the B load consumed in the same window:
//   LOADB(s+1); CLUSTER0; x0,x1; LOADB(s+2); CLUSTER1; x2,x3;
//   LOADB(s+3); CLUSTER2; LOADB(s+4); CLUSTER3; commits(x-wait); barrier.
// Each B-wait now only drains B (~250cy L2, covered by previous cluster);
// x drains once, at the commit, with ~2 clusters of slack.
//  - B never touches LDS: Wb2 fragment-major, coalesced 1KB wave loads, L2.
//  - LDS = A-frags only: 16 KB dbuf; barrier drain finds nothing young.
//  - 512 blocks x 512 thr (32 rows x 512 cols/block, x read from HBM once),
//    2 blocks/CU, 4 waves/SIMD. VGPR ~105 < 128 cap.

#define BATCH  16384
#define UNITS  512
#define KDIM   4096
#define KSTEP  64
#define NSTEP  (KDIM / KSTEP)   // 64
#define NPER   (NSTEP / 4)      // 16 quad-periods
#define MROWS  32               // rows per block

typedef int v4i  __attribute__((ext_vector_type(4)));
typedef int v16i __attribute__((ext_vector_type(16)));

// ---- pack W: f32 [4096][512] -> Wb2 fragment-major i8 +/-1 (2 MB) ----------
// 16B chunk index ((s*16 + n5)*2 + ks)*64 + lane; lane = (n&31) + 32*k16half;
// covers col n5*32+(n&31), k = s*64 + ks*32 + k16half*16 + [0..15].
__global__ __launch_bounds__(256) void pack_w_kernel(const float* __restrict__ W,
                                                     uint8_t* __restrict__ Wb2) {
    int t  = blockIdx.x * 256 + threadIdx.x;   // 0..262143
    int n  = t & 511;                          // col
    int k0 = (t >> 9) * 8;                     // 8 consecutive k
    unsigned long long m = 0;
    #pragma unroll
    for (int j = 0; j < 8; ++j) {
        float v = W[(size_t)(k0 + j) * UNITS + n];
        m |= ((v < 0.f) ? 0xFFull : 0x01ull) << (8 * j);
    }
    int s  = k0 >> 6;
    int kk = k0 & 63;
    int ks = kk >> 5;
    int hi = (kk & 31) >> 4;
    int lane = (n & 31) + 32 * hi;
    size_t a = ((((size_t)s * 16 + (n >> 5)) * 2 + ks) * 64 + lane) * 16 + (kk & 15);
    *reinterpret_cast<unsigned long long*>(Wb2 + a) = m;
}

__device__ __forceinline__ uint32_t sgn4(float4 v) {
    uint32_t b0 = v.x < 0.f ? 0xFFu : 0x01u;
    uint32_t b1 = v.y < 0.f ? 0xFFu : 0x01u;
    uint32_t b2 = v.z < 0.f ? 0xFFu : 0x01u;
    uint32_t b3 = v.w < 0.f ? 0xFFu : 0x01u;
    return b0 | (b1 << 8) | (b2 << 16) | (b3 << 24);
}

// load one step's 4 B-fragments (ct0ks0, ct0ks1, ct1ks0, ct1ks1)
#define LOADB(D0, D1, D2, D3, S)                                               \
    {                                                                          \
        const uint8_t* _b = bbase + (size_t)(S) * 32768;                       \
        D0 = *reinterpret_cast<const v4i*>(_b);                                \
        D1 = *reinterpret_cast<const v4i*>(_b + 1024);                         \
        D2 = *reinterpret_cast<const v4i*>(_b + 2048);                         \
        D3 = *reinterpret_cast<const v4i*>(_b + 3072);                         \
    }

// one K-step's MFMA cluster: A-frags FI0/FI1 of buffer PB, B regs B0..B3
#define CLUSTER(PB, FI0, FI1, B0, B1, B2, B3)                                  \
    {                                                                          \
        v4i af0 = *reinterpret_cast<const v4i*>(&Af[(PB) * 8192 + (FI0) * 1024 + l * 16]); \
        v4i af1 = *reinterpret_cast<const v4i*>(&Af[(PB) * 8192 + (FI1) * 1024 + l * 16]); \
        __builtin_amdgcn_s_setprio(1);                                         \
        acc0 = __builtin_amdgcn_mfma_i32_32x32x32_i8(af0, B0, acc0, 0, 0, 0);  \
        acc0 = __builtin_amdgcn_mfma_i32_32x32x32_i8(af1, B1, acc0, 0, 0, 0);  \
        acc1 = __builtin_amdgcn_mfma_i32_32x32x32_i8(af0, B2, acc1, 0, 0, 0);  \
        acc1 = __builtin_amdgcn_mfma_i32_32x32x32_i8(af1, B3, acc1, 0, 0, 0);  \
        __builtin_amdgcn_s_setprio(0);                                         \
    }

// one quad-period: steps 4Q..4Q+3 read Af[PB]; commits A(4Q+4..+7) -> Af[PB^1]
// x loads issued AFTER the B loads they must not block (vmcnt order fix).
#define PERIOD(Q, PB)                                                          \
    {                                                                          \
        const int _s4 = 4 * (Q) + 4;                                           \
        LOADB(bp1a, bp1b, bp1c, bp1d, 4 * (Q) + 1);                            \
        CLUSTER(PB, 0, 1, bp0a, bp0b, bp0c, bp0d);                             \
        float4 xq0 = *reinterpret_cast<const float4*>(                         \
            xrow + (size_t)((_s4     < NSTEP) ? _s4     : NSTEP - 1) * KSTEP); \
        float4 xq1 = *reinterpret_cast<const float4*>(                         \
            xrow + (size_t)((_s4 + 1 < NSTEP) ? _s4 + 1 : NSTEP - 1) * KSTEP); \
        LOADB(bp0a, bp0b, bp0c, bp0d, 4 * (Q) + 2);                            \
        CLUSTER(PB, 2, 3, bp1a, bp1b, bp1c, bp1d);                             \
        float4 xq2 = *reinterpret_cast<const float4*>(                         \
            xrow + (size_t)((_s4 + 2 < NSTEP) ? _s4 + 2 : NSTEP - 1) * KSTEP); \
        float4 xq3 = *reinterpret_cast<const float4*>(                         \
            xrow + (size_t)((_s4 + 3 < NSTEP) ? _s4 + 3 : NSTEP - 1) * KSTEP); \
        LOADB(bp1a, bp1b, bp1c, bp1d, 4 * (Q) + 3);                            \
        CLUSTER(PB, 4, 5, bp0a, bp0b, bp0c, bp0d);                             \
        LOADB(bp0a, bp0b, bp0c, bp0d, (_s4 < NSTEP) ? _s4 : NSTEP - 1);        \
        CLUSTER(PB, 6, 7, bp1a, bp1b, bp1c, bp1d);                             \
        uint8_t* _aw = afw + ((PB) ^ 1) * 8192;                                \
        *reinterpret_cast<uint32_t*>(_aw)        = sgn4(xq0);                  \
        *reinterpret_cast<uint32_t*>(_aw + 2048) = sgn4(xq1);                  \
        *reinterpret_cast<uint32_t*>(_aw + 4096) = sgn4(xq2);                  \
        *reinterpret_cast<uint32_t*>(_aw + 6144) = sgn4(xq3);                  \
        __syncthreads();                                                       \
    }

// ------------------------------- MFMA GEMM ----------------------------------
__global__ __launch_bounds__(512, 1) void mm_kernel(const float* __restrict__ x,
                                                    const uint8_t* __restrict__ Wb2,
                                                    const float* __restrict__ bias,
                                                    float* __restrict__ C) {
    __shared__ __attribute__((aligned(16))) uint8_t Af[2 * 8 * 1024];  // 16 KB
    const int t   = threadIdx.x;
    const int l   = t & 63;
    const int wv  = t >> 6;              // wave 0..7 -> cols wv*64..+63
    const int lr  = l & 31;
    const int hi  = l >> 5;
    const int row0 = blockIdx.x * MROWS;
    // A staging: thread t owns row ar, float4 at k-offset ak of each step
    const int ar = t >> 4;               // 0..31
    const int ak = (t & 15) * 4;         // 0..60
    const int a_lane = (ar & 31) + 32 * ((ak >> 4) & 1);
    const int a_ks   = ak >> 5;
    const int a_off  = ak & 15;
    // commit base: frag (e*2 + a_ks) of buffer B at afw + B*8192 + e*2048
    uint8_t* afw = &Af[a_ks * 1024 + a_lane * 16 + a_off];
    const float* xrow = x + (size_t)(row0 + ar) * KDIM + ak;
    const uint8_t* bbase = Wb2 + ((size_t)(wv * 2) * 2 * 64 + l) * 16;

    v16i acc0, acc1;
    #pragma unroll
    for (int e = 0; e < 16; ++e) { acc0[e] = 0; acc1[e] = 0; }

    v4i bp0a, bp0b, bp0c, bp0d, bp1a, bp1b, bp1c, bp1d;

    // ---- prologue: B(0) first, then x(0..3); commit A(0..3) -> Af[0] ----
    {
        LOADB(bp0a, bp0b, bp0c, bp0d, 0);
        float4 x0 = *reinterpret_cast<const float4*>(xrow);
        float4 x1 = *reinterpret_cast<const float4*>(xrow + KSTEP);
        float4 x2 = *reinterpret_cast<const float4*>(xrow + 2 * KSTEP);
        float4 x3 = *reinterpret_cast<const float4*>(xrow + 3 * KSTEP);
        *reinterpret_cast<uint32_t*>(afw)        = sgn4(x0);
        *reinterpret_cast<uint32_t*>(afw + 2048) = sgn4(x1);
        *reinterpret_cast<uint32_t*>(afw + 4096) = sgn4(x2);
        *reinterpret_cast<uint32_t*>(afw + 6144) = sgn4(x3);
        __syncthreads();
    }

    #pragma unroll 1
    for (int q = 0; q < NPER; q += 2) {
        PERIOD(q,     0);
        PERIOD(q + 1, 1);
    }

    // ---- epilogue: C = acc + bias (verified C/D map) ----
    #pragma unroll
    for (int ct = 0; ct < 2; ++ct) {
        const int col = wv * 64 + ct * 32 + lr;
        const float bv = bias[col];
        const v16i& a = ct ? acc1 : acc0;
        #pragma unroll
        for (int r = 0; r < 16; ++r) {
            int row = row0 + (r & 3) + 8 * (r >> 2) + 4 * hi;
            C[(size_t)row * UNITS + col] = (float)a[r] + bv;
        }
    }
}

extern "C" void kernel_launch(void* const* d_in, const int* in_sizes, int n_in,
                              void* d_out, int out_size, void* d_ws, size_t ws_size,
                              hipStream_t stream) {
    const float* x = (const float*)d_in[0];
    const float* W = (const float*)d_in[1];
    const float* b = (const float*)d_in[2];
    float* out = (float*)d_out;

    uint8_t* Wb2 = (uint8_t*)d_ws;   // 2 MB fragment-major packed W

    pack_w_kernel<<<(512 * 512) / 256, 256, 0, stream>>>(W, Wb2);
    mm_kernel<<<BATCH / MROWS, 512, 0, stream>>>(x, Wb2, b, out);
}